// Round 17
// baseline (241.431 us; speedup 1.0000x reference)
//
#include <hip/hip_runtime.h>
#include <hip/hip_bf16.h>

#define B_  4
#define T_  2048
#define C_  1024
#define H_  16
#define D_  64
#define C3_ 3072

typedef __attribute__((ext_vector_type(8))) short bf16x8;
typedef __attribute__((ext_vector_type(4))) float f32x4;
typedef unsigned short u16;

#define CSCALE 0.1803368801111204f   /* (1/8) * log2(e) */

__device__ __forceinline__ u16 f2bf(float f) {
  union { float f; unsigned int u; } v; v.f = f;
  unsigned int r = (v.u + 0x7FFFu + ((v.u >> 16) & 1u)) >> 16;
  return (u16)r;
}

__device__ __forceinline__ void gload16(void* l, const void* g) {
  __builtin_amdgcn_global_load_lds(
      (const __attribute__((address_space(1))) unsigned int*)g,
      (__attribute__((address_space(3))) unsigned int*)l, 16, 0, 0);
}

// ---------------------------------------------------------------------------
// prep: fused input convert (blocks 0-4095) + both weight transposes.
// ---------------------------------------------------------------------------
__global__ __launch_bounds__(256)
void prep(const float* __restrict__ x, u16* __restrict__ xb,
          const float* __restrict__ wa, u16* __restrict__ waT,
          const float* __restrict__ wp, u16* __restrict__ wpT) {
  const int bid = blockIdx.x;
  const int tid = threadIdx.x;
  if (bid < 4096) {
    const int i = bid * 256 + tid;
    float4 a = *(const float4*)(x + (size_t)i * 8);
    float4 b = *(const float4*)(x + (size_t)i * 8 + 4);
    ushort4 lo, hi;
    lo.x = f2bf(a.x); lo.y = f2bf(a.y); lo.z = f2bf(a.z); lo.w = f2bf(a.w);
    hi.x = f2bf(b.x); hi.y = f2bf(b.y); hi.z = f2bf(b.z); hi.w = f2bf(b.w);
    *(ushort4*)(xb + (size_t)i * 8) = lo;
    *(ushort4*)(xb + (size_t)i * 8 + 4) = hi;
  } else {
    const int b2 = bid - 4096;
    const int bx = b2 & 63, by = b2 >> 6;
    const float* w; u16* wT; int N, n;
    if (bx < 48) { w = wa; wT = waT; N = C3_; n = bx * 64 + (tid & 63); }
    else         { w = wp; wT = wpT; N = C_;  n = (bx - 48) * 64 + (tid & 63); }
    const int k0 = by * 16 + (tid >> 6) * 4;
    float v0 = w[(size_t)(k0 + 0) * N + n];
    float v1 = w[(size_t)(k0 + 1) * N + n];
    float v2 = w[(size_t)(k0 + 2) * N + n];
    float v3 = w[(size_t)(k0 + 3) * N + n];
    ushort4 o; o.x = f2bf(v0); o.y = f2bf(v1); o.z = f2bf(v2); o.w = f2bf(v3);
    *(ushort4*)(wT + (size_t)n * 1024 + k0) = o;
  }
}

// ---------------------------------------------------------------------------
// 8-phase GEMM (T3+T4+T5), race-fixed schedule, templated tile height.
// VSPLIT epilogue writes v columns transposed into vT. (unchanged)
// ---------------------------------------------------------------------------
template <typename OutT, int BM, bool VSPLIT>
__global__ __launch_bounds__(512, 2)
void gemm256(const u16* __restrict__ A, const u16* __restrict__ Bt,
             const float* __restrict__ bias, OutT* __restrict__ C,
             u16* __restrict__ vTout, int M, int N, int K, int qscale_cols) {
  constexpr int AG = BM * 8;
  constexpr int S  = AG + 2048;
  constexpr int MF = BM / 64;
  constexpr int ALOADS = BM / 128;
  __shared__ int4 lds[2 * S];

  const int tid = threadIdx.x, lane = tid & 63, wid = tid >> 6;
  const int wr = wid >> 2, wc = wid & 3;
  const int row0 = blockIdx.y * BM, col0 = blockIdx.x * 256;

  f32x4 acc[2 * MF][4];
#pragma unroll
  for (int m = 0; m < 2 * MF; ++m)
#pragma unroll
    for (int nf = 0; nf < 4; ++nf) acc[m][nf] = (f32x4){0.f, 0.f, 0.f, 0.f};

  const u16* pA[2][ALOADS]; const u16* pB[2][2];
#pragma unroll
  for (int h = 0; h < 2; ++h) {
#pragma unroll
    for (int i = 0; i < ALOADS; ++i) {
      int g = h * (AG / 2) + i * 512 + tid;
      int rr = ((g >> 7) << 4) + (g & 15), ko = ((g >> 4) & 7) * 8;
      pA[h][i] = A + (size_t)(row0 + rr) * K + ko;
    }
#pragma unroll
    for (int i = 0; i < 2; ++i) {
      int g = h * 1024 + i * 512 + tid;
      int rr = ((g >> 7) << 4) + (g & 15), ko = ((g >> 4) & 7) * 8;
      pB[h][i] = Bt + (size_t)(col0 + rr) * K + ko;
    }
  }

  auto stage = [&](int t, int isA, int h, int buf) {
    if (isA) {
      int4* d = &lds[buf * S + h * (AG / 2) + wid * 64];
      gload16(d, pA[h][0] + t * 64);
      if constexpr (ALOADS == 2) gload16(d + 512, pA[h][1] + t * 64);
    } else {
      int4* d = &lds[buf * S + AG + h * 1024 + wid * 64];
      gload16(d, pB[h][0] + t * 64);
      gload16(d + 512, pB[h][1] + t * 64);
    }
  };
  auto rdA = [&](int f, int kk, int buf) {
    return *(const bf16x8*)&lds[buf * S + (wr * (2 * MF) + f) * 128 + kk * 64 + lane];
  };
  auto rdB = [&](int nf, int kk, int buf) {
    return *(const bf16x8*)&lds[buf * S + AG + (wc * 4 + nf) * 128 + kk * 64 + lane];
  };

#define WAIT_KEEP() do { if constexpr (BM == 256) \
    asm volatile("s_waitcnt vmcnt(6)" ::: "memory"); else \
    asm volatile("s_waitcnt vmcnt(5)" ::: "memory"); } while (0)

  const int nk = K >> 6, nit = nk >> 1;

  stage(0, 1, 0, 0); stage(0, 1, 1, 0); stage(0, 0, 0, 0); stage(0, 0, 1, 0);
  stage(1, 0, 0, 1); stage(1, 0, 1, 1); stage(1, 1, 0, 1);
  WAIT_KEEP();
  __builtin_amdgcn_s_barrier();

  for (int it = 0; it < nit; ++it) {
    const int t1g = 2 * it + 1, t2g = t1g + 1, t3g = t1g + 2;
    bf16x8 a0[MF][2], a1[MF][2], b0[2][2], b1[2][2];

    // ===== K-tile 2it (buf0) =====
#pragma unroll
    for (int m = 0; m < MF; ++m) { a0[m][0] = rdA(m, 0, 0); a0[m][1] = rdA(m, 1, 0); }
#pragma unroll
    for (int nf = 0; nf < 2; ++nf) { b0[nf][0] = rdB(nf, 0, 0); b0[nf][1] = rdB(nf, 1, 0); }
    stage(t1g, 1, 1, 1);
    __builtin_amdgcn_s_barrier();
    __builtin_amdgcn_s_setprio(1);
#pragma unroll
    for (int m = 0; m < MF; ++m)
#pragma unroll
      for (int nf = 0; nf < 2; ++nf) {
        acc[m][nf] = __builtin_amdgcn_mfma_f32_16x16x32_bf16(a0[m][0], b0[nf][0], acc[m][nf], 0, 0, 0);
        acc[m][nf] = __builtin_amdgcn_mfma_f32_16x16x32_bf16(a0[m][1], b0[nf][1], acc[m][nf], 0, 0, 0);
      }
    __builtin_amdgcn_s_setprio(0);
    __builtin_amdgcn_s_barrier();

#pragma unroll
    for (int nf = 0; nf < 2; ++nf) { b1[nf][0] = rdB(2 + nf, 0, 0); b1[nf][1] = rdB(2 + nf, 1, 0); }
    __builtin_amdgcn_s_barrier();
    __builtin_amdgcn_s_setprio(1);
#pragma unroll
    for (int m = 0; m < MF; ++m)
#pragma unroll
      for (int nf = 0; nf < 2; ++nf) {
        acc[m][2 + nf] = __builtin_amdgcn_mfma_f32_16x16x32_bf16(a0[m][0], b1[nf][0], acc[m][2 + nf], 0, 0, 0);
        acc[m][2 + nf] = __builtin_amdgcn_mfma_f32_16x16x32_bf16(a0[m][1], b1[nf][1], acc[m][2 + nf], 0, 0, 0);
      }
    __builtin_amdgcn_s_setprio(0);
    __builtin_amdgcn_s_barrier();

#pragma unroll
    for (int m = 0; m < MF; ++m) { a1[m][0] = rdA(MF + m, 0, 0); a1[m][1] = rdA(MF + m, 1, 0); }
    if (t2g < nk) stage(t2g, 0, 0, 0);
    __builtin_amdgcn_s_barrier();
    __builtin_amdgcn_s_setprio(1);
#pragma unroll
    for (int m = 0; m < MF; ++m)
#pragma unroll
      for (int nf = 0; nf < 2; ++nf) {
        acc[MF + m][2 + nf] = __builtin_amdgcn_mfma_f32_16x16x32_bf16(a1[m][0], b1[nf][0], acc[MF + m][2 + nf], 0, 0, 0);
        acc[MF + m][2 + nf] = __builtin_amdgcn_mfma_f32_16x16x32_bf16(a1[m][1], b1[nf][1], acc[MF + m][2 + nf], 0, 0, 0);
      }
    __builtin_amdgcn_s_setprio(0);
    __builtin_amdgcn_s_barrier();

    if (t2g < nk) {
      stage(t2g, 0, 1, 0);
      stage(t2g, 1, 0, 0);
      WAIT_KEEP();
    } else {
      asm volatile("s_waitcnt vmcnt(0)" ::: "memory");
    }
    __builtin_amdgcn_s_barrier();
    __builtin_amdgcn_s_setprio(1);
#pragma unroll
    for (int m = 0; m < MF; ++m)
#pragma unroll
      for (int nf = 0; nf < 2; ++nf) {
        acc[MF + m][nf] = __builtin_amdgcn_mfma_f32_16x16x32_bf16(a1[m][0], b0[nf][0], acc[MF + m][nf], 0, 0, 0);
        acc[MF + m][nf] = __builtin_amdgcn_mfma_f32_16x16x32_bf16(a1[m][1], b0[nf][1], acc[MF + m][nf], 0, 0, 0);
      }
    __builtin_amdgcn_s_setprio(0);
    __builtin_amdgcn_s_barrier();

    // ===== K-tile 2it+1 (buf1) =====
#pragma unroll
    for (int m = 0; m < MF; ++m) { a0[m][0] = rdA(m, 0, 1); a0[m][1] = rdA(m, 1, 1); }
#pragma unroll
    for (int nf = 0; nf < 2; ++nf) { b0[nf][0] = rdB(nf, 0, 1); b0[nf][1] = rdB(nf, 1, 1); }
    if (t2g < nk) stage(t2g, 1, 1, 0);
    __builtin_amdgcn_s_barrier();
    __builtin_amdgcn_s_setprio(1);
#pragma unroll
    for (int m = 0; m < MF; ++m)
#pragma unroll
      for (int nf = 0; nf < 2; ++nf) {
        acc[m][nf] = __builtin_amdgcn_mfma_f32_16x16x32_bf16(a0[m][0], b0[nf][0], acc[m][nf], 0, 0, 0);
        acc[m][nf] = __builtin_amdgcn_mfma_f32_16x16x32_bf16(a0[m][1], b0[nf][1], acc[m][nf], 0, 0, 0);
      }
    __builtin_amdgcn_s_setprio(0);
    __builtin_amdgcn_s_barrier();

#pragma unroll
    for (int nf = 0; nf < 2; ++nf) { b1[nf][0] = rdB(2 + nf, 0, 1); b1[nf][1] = rdB(2 + nf, 1, 1); }
    __builtin_amdgcn_s_barrier();
    __builtin_amdgcn_s_setprio(1);
#pragma unroll
    for (int m = 0; m < MF; ++m)
#pragma unroll
      for (int nf = 0; nf < 2; ++nf) {
        acc[m][2 + nf] = __builtin_amdgcn_mfma_f32_16x16x32_bf16(a0[m][0], b1[nf][0], acc[m][2 + nf], 0, 0, 0);
        acc[m][2 + nf] = __builtin_amdgcn_mfma_f32_16x16x32_bf16(a0[m][1], b1[nf][1], acc[m][2 + nf], 0, 0, 0);
      }
    __builtin_amdgcn_s_setprio(0);
    __builtin_amdgcn_s_barrier();

#pragma unroll
    for (int m = 0; m < MF; ++m) { a1[m][0] = rdA(MF + m, 0, 1); a1[m][1] = rdA(MF + m, 1, 1); }
    if (t3g < nk) stage(t3g, 0, 0, 1);
    __builtin_amdgcn_s_barrier();
    __builtin_amdgcn_s_setprio(1);
#pragma unroll
    for (int m = 0; m < MF; ++m)
#pragma unroll
      for (int nf = 0; nf < 2; ++nf) {
        acc[MF + m][2 + nf] = __builtin_amdgcn_mfma_f32_16x16x32_bf16(a1[m][0], b1[nf][0], acc[MF + m][2 + nf], 0, 0, 0);
        acc[MF + m][2 + nf] = __builtin_amdgcn_mfma_f32_16x16x32_bf16(a1[m][1], b1[nf][1], acc[MF + m][2 + nf], 0, 0, 0);
      }
    __builtin_amdgcn_s_setprio(0);
    __builtin_amdgcn_s_barrier();

    if (t3g < nk) {
      stage(t3g, 0, 1, 1);
      stage(t3g, 1, 0, 1);
      WAIT_KEEP();
    } else {
      asm volatile("s_waitcnt vmcnt(0)" ::: "memory");
    }
    __builtin_amdgcn_s_barrier();
    __builtin_amdgcn_s_setprio(1);
#pragma unroll
    for (int m = 0; m < MF; ++m)
#pragma unroll
      for (int nf = 0; nf < 2; ++nf) {
        acc[MF + m][nf] = __builtin_amdgcn_mfma_f32_16x16x32_bf16(a1[m][0], b0[nf][0], acc[MF + m][nf], 0, 0, 0);
        acc[MF + m][nf] = __builtin_amdgcn_mfma_f32_16x16x32_bf16(a1[m][1], b0[nf][1], acc[MF + m][nf], 0, 0, 0);
      }
    __builtin_amdgcn_s_setprio(0);
    __builtin_amdgcn_s_barrier();
  }
#undef WAIT_KEEP

  const int cc = lane & 15, qg = lane >> 4;
#pragma unroll
  for (int m = 0; m < 2 * MF; ++m) {
#pragma unroll
    for (int nf = 0; nf < 4; ++nf) {
      const int gc = col0 + wc * 64 + nf * 16 + cc;
      const float bv = bias[gc];
      const int gr0 = row0 + wr * (BM / 2) + m * 16 + qg * 4;
      if (VSPLIT && gc >= 2 * C_) {
        const int hh = (gc - 2 * C_) >> 6, d = (gc - 2 * C_) & 63;
        const int bb = gr0 >> 11, tloc = gr0 & 2047;
        ushort4 pk;
        pk.x = f2bf(acc[m][nf][0] + bv);
        pk.y = f2bf(acc[m][nf][1] + bv);
        pk.z = f2bf(acc[m][nf][2] + bv);
        pk.w = f2bf(acc[m][nf][3] + bv);
        *(ushort4*)(vTout + ((size_t)(bb * 16 + hh) * 64 + d) * T_ + tloc) = pk;
      } else {
        const float sc = (gc < qscale_cols) ? CSCALE : 1.0f;
#pragma unroll
        for (int r = 0; r < 4; ++r) {
          float val = (acc[m][nf][r] + bv) * sc;
          if constexpr (sizeof(OutT) == 2)
            ((u16*)C)[(size_t)(gr0 + r) * N + gc] = f2bf(val);
          else
            ((float*)C)[(size_t)(gr0 + r) * N + gc] = val;
        }
      }
    }
  }
}

// ---------------------------------------------------------------------------
// Flash attention v11: R11 body with ADJACENT causal pairing — waves 0-3 ->
// q-tile 2*ip, waves 4-7 -> q-tile 2*ip+1, staging span jn = 4*ip+4.
// Total staged tiles per (b,h): 144 vs 200 for the (ip,15-ip) pairing
// (-28% staging iterations & barriers); compute identical.
// ---------------------------------------------------------------------------
__global__ __launch_bounds__(512, 4)
void attn_mfma(const u16* __restrict__ qkv, const u16* __restrict__ vT,
               u16* __restrict__ yout) {
  __shared__ int4 Ks4[512];
  __shared__ int4 Vs4[512];
  __shared__ int4 Ps4[2048];

  const int n   = blockIdx.x;
  const int xcd = n & 7, t = n >> 3;
  const int bh  = xcd * 8 + (t >> 3);
  const int ip  = t & 7;
  const int b   = bh >> 4, h = bh & 15;

  const int tid = threadIdx.x;
  const int lane = tid & 63, wq = tid >> 6;
  const int sub = wq & 3;
  const int cc = lane & 15, qg = lane >> 4;

  const int qt128 = 2 * ip + (wq >> 2);          // adjacent pair
  const int qrow0 = qt128 * 128 + sub * 32;
  const int diag  = qt128 * 2 + (sub >> 1);
  const int jn    = 4 * ip + 4;                  // staging span of the pair

  const u16* kbase = qkv + (size_t)b * T_ * C3_ + C_ + h * D_;
  const u16* vtb   = vT + (size_t)bh * D_ * T_;

  bf16x8 qf[2][2];
#pragma unroll
  for (int hf = 0; hf < 2; ++hf) {
    const u16* qb = qkv + (size_t)(b * T_ + qrow0 + hf * 16 + cc) * C3_ + h * D_;
    qf[hf][0] = *(const bf16x8*)(qb + qg * 8);
    qf[hf][1] = *(const bf16x8*)(qb + 32 + qg * 8);
  }

  const u16* kg = kbase + (size_t)((tid >> 7) * 16 + (tid & 15)) * C3_ +
                  ((tid >> 6) & 1) * 32 + ((tid >> 4) & 3) * 8;
  const u16* vg = vtb + (size_t)((tid >> 7) * 16 + (tid & 15)) * T_ +
                  ((tid >> 6) & 1) * 32 + ((tid >> 4) & 3) * 8;

  int4 kpref = *(const int4*)kg;
  int4 vpref = *(const int4*)vg;

  float m_r[2] = {-1e30f, -1e30f}, l_r[2] = {0.f, 0.f};
  f32x4 o[2][4];
#pragma unroll
  for (int hf = 0; hf < 2; ++hf)
#pragma unroll
    for (int db = 0; db < 4; ++db) o[hf][db] = (f32x4){0.f, 0.f, 0.f, 0.f};

  for (int j = 0; j < jn; ++j) {
    __syncthreads();
    Ks4[tid] = kpref;
    Vs4[tid] = vpref;
    __syncthreads();
    if (j + 1 < jn) {
      kpref = *(const int4*)(kg + (size_t)(j + 1) * 64 * C3_);
      vpref = *(const int4*)(vg + (j + 1) * 64);
    }
    if (j > diag) continue;

    __builtin_amdgcn_s_setprio(1);
    f32x4 s[2][4];
#pragma unroll
    for (int kb = 0; kb < 4; ++kb) {
      bf16x8 kf0 = *(const bf16x8*)(Ks4 + kb * 128 + lane);
      bf16x8 kf1 = *(const bf16x8*)(Ks4 + kb * 128 + 64 + lane);
#pragma unroll
      for (int hf = 0; hf < 2; ++hf) {
        f32x4 z = (f32x4){0.f, 0.f, 0.f, 0.f};
        z = __builtin_amdgcn_mfma_f32_16x16x32_bf16(kf0, qf[hf][0], z, 0, 0, 0);
        z = __builtin_amdgcn_mfma_f32_16x16x32_bf16(kf1, qf[hf][1], z, 0, 0, 0);
        s[hf][kb] = z;
      }
    }
    __builtin_amdgcn_s_setprio(0);

    if (j == diag) {
#pragma unroll
      for (int hf = 0; hf < 2; ++hf) {
        const int qabs = qrow0 + hf * 16 + cc;
#pragma unroll
        for (int kb = 0; kb < 4; ++kb)
#pragma unroll
          for (int r = 0; r < 4; ++r)
            if ((j * 64 + kb * 16 + qg * 4 + r) > qabs) s[hf][kb][r] = -1e30f;
      }
    }

#pragma unroll
    for (int hf = 0; hf < 2; ++hf) {
      float mx = s[hf][0][0];
#pragma unroll
      for (int kb = 0; kb < 4; ++kb)
#pragma unroll
        for (int r = 0; r < 4; ++r) mx = fmaxf(mx, s[hf][kb][r]);
      mx = fmaxf(mx, __shfl_xor(mx, 16));
      mx = fmaxf(mx, __shfl_xor(mx, 32));

      if (!__all(mx <= m_r[hf])) {
        float mn = fmaxf(m_r[hf], mx);
        float al = exp2f(m_r[hf] - mn);
        m_r[hf] = mn;
        l_r[hf] *= al;
        float alq[4];
#pragma unroll
        for (int r = 0; r < 4; ++r)
          alq[r] = __shfl(al, (lane & 48) | (qg * 4 + r));
#pragma unroll
        for (int db = 0; db < 4; ++db)
#pragma unroll
          for (int r = 0; r < 4; ++r) o[hf][db][r] *= alq[r];
      }

      float lsum = 0.f;
#pragma unroll
      for (int kb = 0; kb < 4; ++kb)
#pragma unroll
        for (int r = 0; r < 4; ++r) {
          float p = exp2f(s[hf][kb][r] - m_r[hf]);
          s[hf][kb][r] = p;
          lsum += p;
        }
      l_r[hf] += lsum;

      char* myPb = (char*)(Ps4 + wq * 256 + hf * 128);
#pragma unroll
      for (int kb = 0; kb < 4; ++kb) {
        unsigned plo, phi;
        asm("v_cvt_pk_bf16_f32 %0, %1, %2" : "=v"(plo) : "v"(s[hf][kb][0]), "v"(s[hf][kb][1]));
        asm("v_cvt_pk_bf16_f32 %0, %1, %2" : "=v"(phi) : "v"(s[hf][kb][2]), "v"(s[hf][kb][3]));
        const int kv0 = kb * 16 + qg * 4;
        const int g = ((kv0 >> 5) << 6) + (((kv0 >> 3) & 3) << 4) + cc;
        uint2 pk; pk.x = plo; pk.y = phi;
        *(uint2*)(myPb + g * 16 + (kv0 & 7) * 2) = pk;
      }
    }

    bf16x8 pa[2][2];
#pragma unroll
    for (int hf = 0; hf < 2; ++hf)
#pragma unroll
      for (int ks = 0; ks < 2; ++ks)
        pa[hf][ks] = *(const bf16x8*)(Ps4 + wq * 256 + hf * 128 + ks * 64 + lane);
    __builtin_amdgcn_s_setprio(1);
#pragma unroll
    for (int db = 0; db < 4; ++db) {
#pragma unroll
      for (int ks = 0; ks < 2; ++ks) {
        bf16x8 vf = *(const bf16x8*)(Vs4 + db * 128 + ks * 64 + lane);
        o[0][db] = __builtin_amdgcn_mfma_f32_16x16x32_bf16(pa[0][ks], vf, o[0][db], 0, 0, 0);
        o[1][db] = __builtin_amdgcn_mfma_f32_16x16x32_bf16(pa[1][ks], vf, o[1][db], 0, 0, 0);
      }
    }
    __builtin_amdgcn_s_setprio(0);
  }

#pragma unroll
  for (int hf = 0; hf < 2; ++hf) {
    float ls = l_r[hf];
    ls += __shfl_xor(ls, 16);
    ls += __shfl_xor(ls, 32);
    float linv_l = 1.0f / ls;
    float linv[4];
#pragma unroll
    for (int r = 0; r < 4; ++r)
      linv[r] = __shfl(linv_l, (lane & 48) | (qg * 4 + r));

    u16* yb = yout + (size_t)(b * T_ + qrow0 + hf * 16 + qg * 4) * C_ + h * D_ + cc;
#pragma unroll
    for (int db = 0; db < 4; ++db)
#pragma unroll
      for (int r = 0; r < 4; ++r)
        yb[(size_t)r * C_ + db * 16] = f2bf(o[hf][db][r] * linv[r]);
  }
}

// ---------------------------------------------------------------------------
extern "C" void kernel_launch(void* const* d_in, const int* in_sizes, int n_in,
                              void* d_out, int out_size, void* d_ws, size_t ws_size,
                              hipStream_t stream) {
  const float* x      = (const float*)d_in[0];
  const float* w_attn = (const float*)d_in[1];
  const float* b_attn = (const float*)d_in[2];
  const float* w_proj = (const float*)d_in[3];
  const float* b_proj = (const float*)d_in[4];
  float* out = (float*)d_out;

  char* ws = (char*)d_ws;
  u16* xb  = (u16*)(ws);                          // 16 MB
  u16* waT = (u16*)(ws + 16777216);               //  6 MB  [3072][1024]
  u16* wpT = (u16*)(ws + 23068672);               //  2 MB  [1024][1024]
  u16* qkv = (u16*)(ws + 25165824);               // 48 MB  [8192][3072] (v region unused)
  u16* yb  = (u16*)(ws + 75497472);               // 16 MB  [8192][1024]
  u16* vT  = (u16*)(ws + 92274688);               // 16 MB  [64][64][2048]

  prep<<<8192, 256, 0, stream>>>(x, xb, w_attn, waT, w_proj, wpT);

  gemm256<u16, 256, true><<<dim3(C3_ / 256, (B_ * T_) / 256), 512, 0, stream>>>(
      xb, waT, b_attn, qkv, vT, B_ * T_, C3_, C_, C_);

  attn_mfma<<<dim3(8 * H_ * B_), 512, 0, stream>>>(qkv, vT, yb);

  gemm256<float, 128, false><<<dim3(C_ / 256, (B_ * T_) / 128), 512, 0, stream>>>(
      yb, wpT, b_proj, out, nullptr, B_ * T_, C_, C_, 0);
}

// Round 18
// 205.873 us; speedup vs baseline: 1.1727x; 1.1727x over previous
//
#include <hip/hip_runtime.h>
#include <hip/hip_bf16.h>

#define B_  4
#define T_  2048
#define C_  1024
#define H_  16
#define D_  64
#define C3_ 3072

typedef __attribute__((ext_vector_type(8))) short bf16x8;
typedef __attribute__((ext_vector_type(4))) float f32x4;
typedef unsigned short u16;

#define CSCALE 0.1803368801111204f   /* (1/8) * log2(e) */

__device__ __forceinline__ u16 f2bf(float f) {
  union { float f; unsigned int u; } v; v.f = f;
  unsigned int r = (v.u + 0x7FFFu + ((v.u >> 16) & 1u)) >> 16;
  return (u16)r;
}

__device__ __forceinline__ void gload16(void* l, const void* g) {
  __builtin_amdgcn_global_load_lds(
      (const __attribute__((address_space(1))) unsigned int*)g,
      (__attribute__((address_space(3))) unsigned int*)l, 16, 0, 0);
}

// ---------------------------------------------------------------------------
// prep: fused input convert (blocks 0-4095) + both weight transposes.
// ---------------------------------------------------------------------------
__global__ __launch_bounds__(256)
void prep(const float* __restrict__ x, u16* __restrict__ xb,
          const float* __restrict__ wa, u16* __restrict__ waT,
          const float* __restrict__ wp, u16* __restrict__ wpT) {
  const int bid = blockIdx.x;
  const int tid = threadIdx.x;
  if (bid < 4096) {
    const int i = bid * 256 + tid;
    float4 a = *(const float4*)(x + (size_t)i * 8);
    float4 b = *(const float4*)(x + (size_t)i * 8 + 4);
    ushort4 lo, hi;
    lo.x = f2bf(a.x); lo.y = f2bf(a.y); lo.z = f2bf(a.z); lo.w = f2bf(a.w);
    hi.x = f2bf(b.x); hi.y = f2bf(b.y); hi.z = f2bf(b.z); hi.w = f2bf(b.w);
    *(ushort4*)(xb + (size_t)i * 8) = lo;
    *(ushort4*)(xb + (size_t)i * 8 + 4) = hi;
  } else {
    const int b2 = bid - 4096;
    const int bx = b2 & 63, by = b2 >> 6;
    const float* w; u16* wT; int N, n;
    if (bx < 48) { w = wa; wT = waT; N = C3_; n = bx * 64 + (tid & 63); }
    else         { w = wp; wT = wpT; N = C_;  n = (bx - 48) * 64 + (tid & 63); }
    const int k0 = by * 16 + (tid >> 6) * 4;
    float v0 = w[(size_t)(k0 + 0) * N + n];
    float v1 = w[(size_t)(k0 + 1) * N + n];
    float v2 = w[(size_t)(k0 + 2) * N + n];
    float v3 = w[(size_t)(k0 + 3) * N + n];
    ushort4 o; o.x = f2bf(v0); o.y = f2bf(v1); o.z = f2bf(v2); o.w = f2bf(v3);
    *(ushort4*)(wT + (size_t)n * 1024 + k0) = o;
  }
}

// ---------------------------------------------------------------------------
// 8-phase GEMM (T3+T4+T5), race-fixed schedule, templated tile height.
// 1D grid + bijective XCD swizzle (T1): consecutive wg within an XCD chunk
// share a row-panel -> per-XCD L2 A-reuse. nwg % 8 == 0 for both shapes.
// VSPLIT epilogue writes v columns transposed into vT.
// ---------------------------------------------------------------------------
template <typename OutT, int BM, bool VSPLIT>
__global__ __launch_bounds__(512, 2)
void gemm256(const u16* __restrict__ A, const u16* __restrict__ Bt,
             const float* __restrict__ bias, OutT* __restrict__ C,
             u16* __restrict__ vTout, int M, int N, int K, int qscale_cols,
             int nbx) {
  constexpr int AG = BM * 8;
  constexpr int S  = AG + 2048;
  constexpr int MF = BM / 64;
  constexpr int ALOADS = BM / 128;
  __shared__ int4 lds[2 * S];

  // XCD swizzle: nwg divisible by 8 -> wg = xcd*(nwg/8) + orig/8
  const int nwg = (int)gridDim.x;
  const int wg  = (blockIdx.x & 7) * (nwg >> 3) + (blockIdx.x >> 3);
  const int bx = wg % nbx, by = wg / nbx;

  const int tid = threadIdx.x, lane = tid & 63, wid = tid >> 6;
  const int wr = wid >> 2, wc = wid & 3;
  const int row0 = by * BM, col0 = bx * 256;

  f32x4 acc[2 * MF][4];
#pragma unroll
  for (int m = 0; m < 2 * MF; ++m)
#pragma unroll
    for (int nf = 0; nf < 4; ++nf) acc[m][nf] = (f32x4){0.f, 0.f, 0.f, 0.f};

  const u16* pA[2][ALOADS]; const u16* pB[2][2];
#pragma unroll
  for (int h = 0; h < 2; ++h) {
#pragma unroll
    for (int i = 0; i < ALOADS; ++i) {
      int g = h * (AG / 2) + i * 512 + tid;
      int rr = ((g >> 7) << 4) + (g & 15), ko = ((g >> 4) & 7) * 8;
      pA[h][i] = A + (size_t)(row0 + rr) * K + ko;
    }
#pragma unroll
    for (int i = 0; i < 2; ++i) {
      int g = h * 1024 + i * 512 + tid;
      int rr = ((g >> 7) << 4) + (g & 15), ko = ((g >> 4) & 7) * 8;
      pB[h][i] = Bt + (size_t)(col0 + rr) * K + ko;
    }
  }

  auto stage = [&](int t, int isA, int h, int buf) {
    if (isA) {
      int4* d = &lds[buf * S + h * (AG / 2) + wid * 64];
      gload16(d, pA[h][0] + t * 64);
      if constexpr (ALOADS == 2) gload16(d + 512, pA[h][1] + t * 64);
    } else {
      int4* d = &lds[buf * S + AG + h * 1024 + wid * 64];
      gload16(d, pB[h][0] + t * 64);
      gload16(d + 512, pB[h][1] + t * 64);
    }
  };
  auto rdA = [&](int f, int kk, int buf) {
    return *(const bf16x8*)&lds[buf * S + (wr * (2 * MF) + f) * 128 + kk * 64 + lane];
  };
  auto rdB = [&](int nf, int kk, int buf) {
    return *(const bf16x8*)&lds[buf * S + AG + (wc * 4 + nf) * 128 + kk * 64 + lane];
  };

#define WAIT_KEEP() do { if constexpr (BM == 256) \
    asm volatile("s_waitcnt vmcnt(6)" ::: "memory"); else \
    asm volatile("s_waitcnt vmcnt(5)" ::: "memory"); } while (0)

  const int nk = K >> 6, nit = nk >> 1;

  stage(0, 1, 0, 0); stage(0, 1, 1, 0); stage(0, 0, 0, 0); stage(0, 0, 1, 0);
  stage(1, 0, 0, 1); stage(1, 0, 1, 1); stage(1, 1, 0, 1);
  WAIT_KEEP();
  __builtin_amdgcn_s_barrier();

  for (int it = 0; it < nit; ++it) {
    const int t1g = 2 * it + 1, t2g = t1g + 1, t3g = t1g + 2;
    bf16x8 a0[MF][2], a1[MF][2], b0[2][2], b1[2][2];

    // ===== K-tile 2it (buf0) =====
#pragma unroll
    for (int m = 0; m < MF; ++m) { a0[m][0] = rdA(m, 0, 0); a0[m][1] = rdA(m, 1, 0); }
#pragma unroll
    for (int nf = 0; nf < 2; ++nf) { b0[nf][0] = rdB(nf, 0, 0); b0[nf][1] = rdB(nf, 1, 0); }
    stage(t1g, 1, 1, 1);
    __builtin_amdgcn_s_barrier();
    __builtin_amdgcn_s_setprio(1);
#pragma unroll
    for (int m = 0; m < MF; ++m)
#pragma unroll
      for (int nf = 0; nf < 2; ++nf) {
        acc[m][nf] = __builtin_amdgcn_mfma_f32_16x16x32_bf16(a0[m][0], b0[nf][0], acc[m][nf], 0, 0, 0);
        acc[m][nf] = __builtin_amdgcn_mfma_f32_16x16x32_bf16(a0[m][1], b0[nf][1], acc[m][nf], 0, 0, 0);
      }
    __builtin_amdgcn_s_setprio(0);
    __builtin_amdgcn_s_barrier();

#pragma unroll
    for (int nf = 0; nf < 2; ++nf) { b1[nf][0] = rdB(2 + nf, 0, 0); b1[nf][1] = rdB(2 + nf, 1, 0); }
    __builtin_amdgcn_s_barrier();
    __builtin_amdgcn_s_setprio(1);
#pragma unroll
    for (int m = 0; m < MF; ++m)
#pragma unroll
      for (int nf = 0; nf < 2; ++nf) {
        acc[m][2 + nf] = __builtin_amdgcn_mfma_f32_16x16x32_bf16(a0[m][0], b1[nf][0], acc[m][2 + nf], 0, 0, 0);
        acc[m][2 + nf] = __builtin_amdgcn_mfma_f32_16x16x32_bf16(a0[m][1], b1[nf][1], acc[m][2 + nf], 0, 0, 0);
      }
    __builtin_amdgcn_s_setprio(0);
    __builtin_amdgcn_s_barrier();

#pragma unroll
    for (int m = 0; m < MF; ++m) { a1[m][0] = rdA(MF + m, 0, 0); a1[m][1] = rdA(MF + m, 1, 0); }
    if (t2g < nk) stage(t2g, 0, 0, 0);
    __builtin_amdgcn_s_barrier();
    __builtin_amdgcn_s_setprio(1);
#pragma unroll
    for (int m = 0; m < MF; ++m)
#pragma unroll
      for (int nf = 0; nf < 2; ++nf) {
        acc[MF + m][2 + nf] = __builtin_amdgcn_mfma_f32_16x16x32_bf16(a1[m][0], b1[nf][0], acc[MF + m][2 + nf], 0, 0, 0);
        acc[MF + m][2 + nf] = __builtin_amdgcn_mfma_f32_16x16x32_bf16(a1[m][1], b1[nf][1], acc[MF + m][2 + nf], 0, 0, 0);
      }
    __builtin_amdgcn_s_setprio(0);
    __builtin_amdgcn_s_barrier();

    if (t2g < nk) {
      stage(t2g, 0, 1, 0);
      stage(t2g, 1, 0, 0);
      WAIT_KEEP();
    } else {
      asm volatile("s_waitcnt vmcnt(0)" ::: "memory");
    }
    __builtin_amdgcn_s_barrier();
    __builtin_amdgcn_s_setprio(1);
#pragma unroll
    for (int m = 0; m < MF; ++m)
#pragma unroll
      for (int nf = 0; nf < 2; ++nf) {
        acc[MF + m][nf] = __builtin_amdgcn_mfma_f32_16x16x32_bf16(a1[m][0], b0[nf][0], acc[MF + m][nf], 0, 0, 0);
        acc[MF + m][nf] = __builtin_amdgcn_mfma_f32_16x16x32_bf16(a1[m][1], b0[nf][1], acc[MF + m][nf], 0, 0, 0);
      }
    __builtin_amdgcn_s_setprio(0);
    __builtin_amdgcn_s_barrier();

    // ===== K-tile 2it+1 (buf1) =====
#pragma unroll
    for (int m = 0; m < MF; ++m) { a0[m][0] = rdA(m, 0, 1); a0[m][1] = rdA(m, 1, 1); }
#pragma unroll
    for (int nf = 0; nf < 2; ++nf) { b0[nf][0] = rdB(nf, 0, 1); b0[nf][1] = rdB(nf, 1, 1); }
    if (t2g < nk) stage(t2g, 1, 1, 0);
    __builtin_amdgcn_s_barrier();
    __builtin_amdgcn_s_setprio(1);
#pragma unroll
    for (int m = 0; m < MF; ++m)
#pragma unroll
      for (int nf = 0; nf < 2; ++nf) {
        acc[m][nf] = __builtin_amdgcn_mfma_f32_16x16x32_bf16(a0[m][0], b0[nf][0], acc[m][nf], 0, 0, 0);
        acc[m][nf] = __builtin_amdgcn_mfma_f32_16x16x32_bf16(a0[m][1], b0[nf][1], acc[m][nf], 0, 0, 0);
      }
    __builtin_amdgcn_s_setprio(0);
    __builtin_amdgcn_s_barrier();

#pragma unroll
    for (int nf = 0; nf < 2; ++nf) { b1[nf][0] = rdB(2 + nf, 0, 1); b1[nf][1] = rdB(2 + nf, 1, 1); }
    __builtin_amdgcn_s_barrier();
    __builtin_amdgcn_s_setprio(1);
#pragma unroll
    for (int m = 0; m < MF; ++m)
#pragma unroll
      for (int nf = 0; nf < 2; ++nf) {
        acc[m][2 + nf] = __builtin_amdgcn_mfma_f32_16x16x32_bf16(a0[m][0], b1[nf][0], acc[m][2 + nf], 0, 0, 0);
        acc[m][2 + nf] = __builtin_amdgcn_mfma_f32_16x16x32_bf16(a0[m][1], b1[nf][1], acc[m][2 + nf], 0, 0, 0);
      }
    __builtin_amdgcn_s_setprio(0);
    __builtin_amdgcn_s_barrier();

#pragma unroll
    for (int m = 0; m < MF; ++m) { a1[m][0] = rdA(MF + m, 0, 1); a1[m][1] = rdA(MF + m, 1, 1); }
    if (t3g < nk) stage(t3g, 0, 0, 1);
    __builtin_amdgcn_s_barrier();
    __builtin_amdgcn_s_setprio(1);
#pragma unroll
    for (int m = 0; m < MF; ++m)
#pragma unroll
      for (int nf = 0; nf < 2; ++nf) {
        acc[MF + m][2 + nf] = __builtin_amdgcn_mfma_f32_16x16x32_bf16(a1[m][0], b1[nf][0], acc[MF + m][2 + nf], 0, 0, 0);
        acc[MF + m][2 + nf] = __builtin_amdgcn_mfma_f32_16x16x32_bf16(a1[m][1], b1[nf][1], acc[MF + m][2 + nf], 0, 0, 0);
      }
    __builtin_amdgcn_s_setprio(0);
    __builtin_amdgcn_s_barrier();

    if (t3g < nk) {
      stage(t3g, 0, 1, 1);
      stage(t3g, 1, 0, 1);
      WAIT_KEEP();
    } else {
      asm volatile("s_waitcnt vmcnt(0)" ::: "memory");
    }
    __builtin_amdgcn_s_barrier();
    __builtin_amdgcn_s_setprio(1);
#pragma unroll
    for (int m = 0; m < MF; ++m)
#pragma unroll
      for (int nf = 0; nf < 2; ++nf) {
        acc[MF + m][nf] = __builtin_amdgcn_mfma_f32_16x16x32_bf16(a1[m][0], b0[nf][0], acc[MF + m][nf], 0, 0, 0);
        acc[MF + m][nf] = __builtin_amdgcn_mfma_f32_16x16x32_bf16(a1[m][1], b0[nf][1], acc[MF + m][nf], 0, 0, 0);
      }
    __builtin_amdgcn_s_setprio(0);
    __builtin_amdgcn_s_barrier();
  }
#undef WAIT_KEEP

  const int cc = lane & 15, qg = lane >> 4;
#pragma unroll
  for (int m = 0; m < 2 * MF; ++m) {
#pragma unroll
    for (int nf = 0; nf < 4; ++nf) {
      const int gc = col0 + wc * 64 + nf * 16 + cc;
      const float bv = bias[gc];
      const int gr0 = row0 + wr * (BM / 2) + m * 16 + qg * 4;
      if (VSPLIT && gc >= 2 * C_) {
        const int hh = (gc - 2 * C_) >> 6, d = (gc - 2 * C_) & 63;
        const int bb = gr0 >> 11, tloc = gr0 & 2047;
        ushort4 pk;
        pk.x = f2bf(acc[m][nf][0] + bv);
        pk.y = f2bf(acc[m][nf][1] + bv);
        pk.z = f2bf(acc[m][nf][2] + bv);
        pk.w = f2bf(acc[m][nf][3] + bv);
        *(ushort4*)(vTout + ((size_t)(bb * 16 + hh) * 64 + d) * T_ + tloc) = pk;
      } else {
        const float sc = (gc < qscale_cols) ? CSCALE : 1.0f;
#pragma unroll
        for (int r = 0; r < 4; ++r) {
          float val = (acc[m][nf][r] + bv) * sc;
          if constexpr (sizeof(OutT) == 2)
            ((u16*)C)[(size_t)(gr0 + r) * N + gc] = f2bf(val);
          else
            ((float*)C)[(size_t)(gr0 + r) * N + gc] = val;
        }
      }
    }
  }
}

// ---------------------------------------------------------------------------
// Flash attention (R11 verbatim — known-good 91 us): 8 waves, 32 q-rows/wave,
// causal-paired 128-row tiles (ip, 15-ip), staged K + pre-transposed V,
// reg-prefetch, swapped QK^T, exp2 softmax, defer-rescale, XCD-bh grouping.
// ---------------------------------------------------------------------------
__global__ __launch_bounds__(512, 4)
void attn_mfma(const u16* __restrict__ qkv, const u16* __restrict__ vT,
               u16* __restrict__ yout) {
  __shared__ int4 Ks4[512];
  __shared__ int4 Vs4[512];
  __shared__ int4 Ps4[2048];

  const int n   = blockIdx.x;
  const int xcd = n & 7, t = n >> 3;
  const int bh  = xcd * 8 + (t >> 3);
  const int ip  = t & 7;
  const int b   = bh >> 4, h = bh & 15;

  const int tid = threadIdx.x;
  const int lane = tid & 63, wq = tid >> 6;
  const int sub = wq & 3;
  const int cc = lane & 15, qg = lane >> 4;

  const int qt128 = (wq < 4) ? ip : (15 - ip);
  const int qrow0 = qt128 * 128 + sub * 32;
  const int diag  = qt128 * 2 + (sub >> 1);
  const int jn    = 32 - 2 * ip;

  const u16* kbase = qkv + (size_t)b * T_ * C3_ + C_ + h * D_;
  const u16* vtb   = vT + (size_t)bh * D_ * T_;

  bf16x8 qf[2][2];
#pragma unroll
  for (int hf = 0; hf < 2; ++hf) {
    const u16* qb = qkv + (size_t)(b * T_ + qrow0 + hf * 16 + cc) * C3_ + h * D_;
    qf[hf][0] = *(const bf16x8*)(qb + qg * 8);
    qf[hf][1] = *(const bf16x8*)(qb + 32 + qg * 8);
  }

  const u16* kg = kbase + (size_t)((tid >> 7) * 16 + (tid & 15)) * C3_ +
                  ((tid >> 6) & 1) * 32 + ((tid >> 4) & 3) * 8;
  const u16* vg = vtb + (size_t)((tid >> 7) * 16 + (tid & 15)) * T_ +
                  ((tid >> 6) & 1) * 32 + ((tid >> 4) & 3) * 8;

  int4 kpref = *(const int4*)kg;
  int4 vpref = *(const int4*)vg;

  float m_r[2] = {-1e30f, -1e30f}, l_r[2] = {0.f, 0.f};
  f32x4 o[2][4];
#pragma unroll
  for (int hf = 0; hf < 2; ++hf)
#pragma unroll
    for (int db = 0; db < 4; ++db) o[hf][db] = (f32x4){0.f, 0.f, 0.f, 0.f};

  for (int j = 0; j < jn; ++j) {
    __syncthreads();
    Ks4[tid] = kpref;
    Vs4[tid] = vpref;
    __syncthreads();
    if (j + 1 < jn) {
      kpref = *(const int4*)(kg + (size_t)(j + 1) * 64 * C3_);
      vpref = *(const int4*)(vg + (j + 1) * 64);
    }
    if (j > diag) continue;

    __builtin_amdgcn_s_setprio(1);
    f32x4 s[2][4];
#pragma unroll
    for (int kb = 0; kb < 4; ++kb) {
      bf16x8 kf0 = *(const bf16x8*)(Ks4 + kb * 128 + lane);
      bf16x8 kf1 = *(const bf16x8*)(Ks4 + kb * 128 + 64 + lane);
#pragma unroll
      for (int hf = 0; hf < 2; ++hf) {
        f32x4 z = (f32x4){0.f, 0.f, 0.f, 0.f};
        z = __builtin_amdgcn_mfma_f32_16x16x32_bf16(kf0, qf[hf][0], z, 0, 0, 0);
        z = __builtin_amdgcn_mfma_f32_16x16x32_bf16(kf1, qf[hf][1], z, 0, 0, 0);
        s[hf][kb] = z;
      }
    }
    __builtin_amdgcn_s_setprio(0);

    if (j == diag) {
#pragma unroll
      for (int hf = 0; hf < 2; ++hf) {
        const int qabs = qrow0 + hf * 16 + cc;
#pragma unroll
        for (int kb = 0; kb < 4; ++kb)
#pragma unroll
          for (int r = 0; r < 4; ++r)
            if ((j * 64 + kb * 16 + qg * 4 + r) > qabs) s[hf][kb][r] = -1e30f;
      }
    }

#pragma unroll
    for (int hf = 0; hf < 2; ++hf) {
      float mx = s[hf][0][0];
#pragma unroll
      for (int kb = 0; kb < 4; ++kb)
#pragma unroll
        for (int r = 0; r < 4; ++r) mx = fmaxf(mx, s[hf][kb][r]);
      mx = fmaxf(mx, __shfl_xor(mx, 16));
      mx = fmaxf(mx, __shfl_xor(mx, 32));

      if (!__all(mx <= m_r[hf])) {
        float mn = fmaxf(m_r[hf], mx);
        float al = exp2f(m_r[hf] - mn);
        m_r[hf] = mn;
        l_r[hf] *= al;
        float alq[4];
#pragma unroll
        for (int r = 0; r < 4; ++r)
          alq[r] = __shfl(al, (lane & 48) | (qg * 4 + r));
#pragma unroll
        for (int db = 0; db < 4; ++db)
#pragma unroll
          for (int r = 0; r < 4; ++r) o[hf][db][r] *= alq[r];
      }

      float lsum = 0.f;
#pragma unroll
      for (int kb = 0; kb < 4; ++kb)
#pragma unroll
        for (int r = 0; r < 4; ++r) {
          float p = exp2f(s[hf][kb][r] - m_r[hf]);
          s[hf][kb][r] = p;
          lsum += p;
        }
      l_r[hf] += lsum;

      char* myPb = (char*)(Ps4 + wq * 256 + hf * 128);
#pragma unroll
      for (int kb = 0; kb < 4; ++kb) {
        unsigned plo, phi;
        asm("v_cvt_pk_bf16_f32 %0, %1, %2" : "=v"(plo) : "v"(s[hf][kb][0]), "v"(s[hf][kb][1]));
        asm("v_cvt_pk_bf16_f32 %0, %1, %2" : "=v"(phi) : "v"(s[hf][kb][2]), "v"(s[hf][kb][3]));
        const int kv0 = kb * 16 + qg * 4;
        const int g = ((kv0 >> 5) << 6) + (((kv0 >> 3) & 3) << 4) + cc;
        uint2 pk; pk.x = plo; pk.y = phi;
        *(uint2*)(myPb + g * 16 + (kv0 & 7) * 2) = pk;
      }
    }

    bf16x8 pa[2][2];
#pragma unroll
    for (int hf = 0; hf < 2; ++hf)
#pragma unroll
      for (int ks = 0; ks < 2; ++ks)
        pa[hf][ks] = *(const bf16x8*)(Ps4 + wq * 256 + hf * 128 + ks * 64 + lane);
    __builtin_amdgcn_s_setprio(1);
#pragma unroll
    for (int db = 0; db < 4; ++db) {
#pragma unroll
      for (int ks = 0; ks < 2; ++ks) {
        bf16x8 vf = *(const bf16x8*)(Vs4 + db * 128 + ks * 64 + lane);
        o[0][db] = __builtin_amdgcn_mfma_f32_16x16x32_bf16(pa[0][ks], vf, o[0][db], 0, 0, 0);
        o[1][db] = __builtin_amdgcn_mfma_f32_16x16x32_bf16(pa[1][ks], vf, o[1][db], 0, 0, 0);
      }
    }
    __builtin_amdgcn_s_setprio(0);
  }

#pragma unroll
  for (int hf = 0; hf < 2; ++hf) {
    float ls = l_r[hf];
    ls += __shfl_xor(ls, 16);
    ls += __shfl_xor(ls, 32);
    float linv_l = 1.0f / ls;
    float linv[4];
#pragma unroll
    for (int r = 0; r < 4; ++r)
      linv[r] = __shfl(linv_l, (lane & 48) | (qg * 4 + r));

    u16* yb = yout + (size_t)(b * T_ + qrow0 + hf * 16 + qg * 4) * C_ + h * D_ + cc;
#pragma unroll
    for (int db = 0; db < 4; ++db)
#pragma unroll
      for (int r = 0; r < 4; ++r)
        yb[(size_t)r * C_ + db * 16] = f2bf(o[hf][db][r] * linv[r]);
  }
}

// ---------------------------------------------------------------------------
extern "C" void kernel_launch(void* const* d_in, const int* in_sizes, int n_in,
                              void* d_out, int out_size, void* d_ws, size_t ws_size,
                              hipStream_t stream) {
  const float* x      = (const float*)d_in[0];
  const float* w_attn = (const float*)d_in[1];
  const float* b_attn = (const float*)d_in[2];
  const float* w_proj = (const float*)d_in[3];
  const float* b_proj = (const float*)d_in[4];
  float* out = (float*)d_out;

  char* ws = (char*)d_ws;
  u16* xb  = (u16*)(ws);                          // 16 MB
  u16* waT = (u16*)(ws + 16777216);               //  6 MB  [3072][1024]
  u16* wpT = (u16*)(ws + 23068672);               //  2 MB  [1024][1024]
  u16* qkv = (u16*)(ws + 25165824);               // 48 MB  [8192][3072] (v region unused)
  u16* yb  = (u16*)(ws + 75497472);               // 16 MB  [8192][1024]
  u16* vT  = (u16*)(ws + 92274688);               // 16 MB  [64][64][2048]

  prep<<<8192, 256, 0, stream>>>(x, xb, w_attn, waT, w_proj, wpT);

  // qkv = x @ w_attn + b_attn; q cols pre-scaled; v cols -> vT (transposed)
  // 1D grid 384 = 12 x 32, XCD-swizzled
  gemm256<u16, 256, true><<<dim3((C3_ / 256) * ((B_ * T_) / 256)), 512, 0, stream>>>(
      xb, waT, b_attn, qkv, vT, B_ * T_, C3_, C_, C_, C3_ / 256);

  attn_mfma<<<dim3(8 * H_ * B_), 512, 0, stream>>>(qkv, vT, yb);

  // proj: BM=128 -> 256 blocks, XCD-swizzled
  gemm256<float, 128, false><<<dim3((C_ / 256) * ((B_ * T_) / 128)), 512, 0, stream>>>(
      yb, wpT, b_proj, out, nullptr, B_ * T_, C_, C_, 0, C_ / 256);
}